// Round 5
// baseline (1243.528 us; speedup 1.0000x reference)
//
#include <hip/hip_runtime.h>
#include <hip/hip_bf16.h>

#define N_NODES 100000
#define E_EDGES 1600000
#define IN_F    256
#define HEADS   4
#define DF      32
#define HD      128           // HEADS*DF
#define NEG_SLOPE 0.2f

typedef __attribute__((ext_vector_type(4))) float f32x4;

// ------ 1. dual GEMM: el = x@w_src+b_src, er = x@w_dst+b_dst (fp32 VALU) ------
// Block 256 thr: 32-row x 128-col tile. tc=tid&31 -> cols tc*4..+3;
// tr=tid>>5 -> rows tr+{0,8,16,24}. K chunked by 64.
__global__ void __launch_bounds__(256)
k_gemm_valu(const float* __restrict__ x,
            const float* __restrict__ w_src, const float* __restrict__ b_src,
            const float* __restrict__ w_dst, const float* __restrict__ b_dst,
            float* __restrict__ el, float* __restrict__ er) {
    __shared__ float xs[32][64];      // 8 KB
    __shared__ float wsv[64][128];    // 32 KB
    __shared__ float wdv[64][128];    // 32 KB

    int tid = threadIdx.x;
    int tc = tid & 31, tr = tid >> 5;
    int row0 = blockIdx.x * 32;

    f32x4 aS[4], aD[4];
    for (int i = 0; i < 4; ++i) {
        aS[i] = (f32x4){0.f, 0.f, 0.f, 0.f};
        aD[i] = (f32x4){0.f, 0.f, 0.f, 0.f};
    }

    for (int kc = 0; kc < IN_F / 64; ++kc) {
        __syncthreads();
        // stage x: 32 rows x 64 k = 512 float4 (2/thread)
        for (int i = 0; i < 2; ++i) {
            int v = i * 256 + tid;
            int r = v >> 4, c = (v & 15) * 4;
            int gr = row0 + r;
            f32x4 val = (f32x4){0.f, 0.f, 0.f, 0.f};
            if (gr < N_NODES)
                val = *(const f32x4*)(x + gr * IN_F + kc * 64 + c);
            *(f32x4*)(&xs[r][c]) = val;
        }
        // stage w chunk: 64 k x 128 n per matrix = 2048 float4 (8/thread each)
        for (int i = 0; i < 8; ++i) {
            int v = i * 256 + tid;
            int k = v >> 5, c = (v & 31) * 4;
            int go = (kc * 64 + k) * HD + c;
            *(f32x4*)(&wsv[k][c]) = *(const f32x4*)(w_src + go);
            *(f32x4*)(&wdv[k][c]) = *(const f32x4*)(w_dst + go);
        }
        __syncthreads();

        for (int kk = 0; kk < 64; ++kk) {
            float x0 = xs[tr][kk];
            float x1 = xs[tr + 8][kk];
            float x2 = xs[tr + 16][kk];
            float x3 = xs[tr + 24][kk];
            f32x4 w0 = *(const f32x4*)(&wsv[kk][tc * 4]);
            f32x4 w1 = *(const f32x4*)(&wdv[kk][tc * 4]);
            aS[0] += x0 * w0; aS[1] += x1 * w0; aS[2] += x2 * w0; aS[3] += x3 * w0;
            aD[0] += x0 * w1; aD[1] += x1 * w1; aD[2] += x2 * w1; aD[3] += x3 * w1;
        }
    }

    f32x4 bs = *(const f32x4*)(b_src + tc * 4);
    f32x4 bd = *(const f32x4*)(b_dst + tc * 4);
    for (int i = 0; i < 4; ++i) {
        int gr = row0 + tr + i * 8;
        if (gr < N_NODES) {
            *(f32x4*)(el + gr * HD + tc * 4) = aS[i] + bs;
            *(f32x4*)(er + gr * HD + tc * 4) = aD[i] + bd;
        }
    }
}

// ------ 2. edge scores: ex = exp(s), denom += ex ------
// 32 lanes per edge; lane l: elements l*4..l*4+3 = head (l>>3), dim (l&7)*4.
__global__ void __launch_bounds__(256)
k_scores(const int* __restrict__ src, const int* __restrict__ dst,
         const float* __restrict__ el, const float* __restrict__ er,
         const float* __restrict__ attn,
         float* __restrict__ p_ex, float* __restrict__ p_denom) {
    int t = blockIdx.x * 256 + threadIdx.x;
    int e = t >> 5;
    if (e >= E_EDGES) return;
    int l = threadIdx.x & 31;
    int s = src[e], d = dst[e];
    float4 ev = *(const float4*)(el + s * HD + l * 4);
    float4 rv = *(const float4*)(er + d * HD + l * 4);
    int h = l >> 3;
    float4 av = *(const float4*)(attn + h * DF + (l & 7) * 4);
    float p = 0.f, tm;
    tm = ev.x + rv.x; tm = tm > 0.f ? tm : NEG_SLOPE * tm; p += av.x * tm;
    tm = ev.y + rv.y; tm = tm > 0.f ? tm : NEG_SLOPE * tm; p += av.y * tm;
    tm = ev.z + rv.z; tm = tm > 0.f ? tm : NEG_SLOPE * tm; p += av.z * tm;
    tm = ev.w + rv.w; tm = tm > 0.f ? tm : NEG_SLOPE * tm; p += av.w * tm;
    // reduce over the 8 lanes of this head
    p += __shfl_xor(p, 1);
    p += __shfl_xor(p, 2);
    p += __shfl_xor(p, 4);
    if ((l & 7) == 0) {
        float exv = expf(p);    // |s| <~ 20 << 88: no max-subtraction needed
        p_ex[e * HEADS + h] = exv;
        atomicAdd(&p_denom[d * HEADS + h], exv);
    }
}

// ------ 3. aggregate: acc[dst] += mean_h(el[src]*a), out1 = mean_h a ------
__global__ void __launch_bounds__(256)
k_aggregate(const int* __restrict__ src, const int* __restrict__ dst,
            const float* __restrict__ el,
            const float* __restrict__ p_ex, const float* __restrict__ p_denom,
            float* __restrict__ acc, float* __restrict__ out1) {
    int t = blockIdx.x * 256 + threadIdx.x;
    int e = t >> 5;
    if (e >= E_EDGES) return;
    int l = threadIdx.x & 31;
    int wl = threadIdx.x & 63;
    int s = src[e], d = dst[e];
    int h = l >> 3;
    float a_h = 0.f;
    if ((l & 7) == 0) a_h = p_ex[e * HEADS + h] / p_denom[d * HEADS + h];
    a_h = __shfl(a_h, (wl >> 3) << 3);    // broadcast within 8-lane cluster
    float4 ev = *(const float4*)(el + s * HD + l * 4);
    float m0 = ev.x * a_h, m1 = ev.y * a_h, m2 = ev.z * a_h, m3 = ev.w * a_h;
    // head-mean: lanes l, l^8, l^16, l^24 hold same din, different head
    m0 += __shfl_xor(m0, 8); m0 += __shfl_xor(m0, 16);
    m1 += __shfl_xor(m1, 8); m1 += __shfl_xor(m1, 16);
    m2 += __shfl_xor(m2, 8); m2 += __shfl_xor(m2, 16);
    m3 += __shfl_xor(m3, 8); m3 += __shfl_xor(m3, 16);
    if (l < 8) {
        float* ap = acc + d * DF + l * 4;
        atomicAdd(ap + 0, m0 * 0.25f);
        atomicAdd(ap + 1, m1 * 0.25f);
        atomicAdd(ap + 2, m2 * 0.25f);
        atomicAdd(ap + 3, m3 * 0.25f);
    }
    float asum = a_h;
    asum += __shfl_xor(asum, 8); asum += __shfl_xor(asum, 16);
    if (l == 0) out1[e] = asum * 0.25f;
}

// ------ 4. finalize: out0 = acc (fp32) ------
__global__ void __launch_bounds__(256)
k_finalize(const float* __restrict__ acc, float* __restrict__ out0) {
    int i = blockIdx.x * 256 + threadIdx.x;
    if (i < N_NODES * DF) out0[i] = acc[i];
}

extern "C" void kernel_launch(void* const* d_in, const int* in_sizes, int n_in,
                              void* d_out, int out_size, void* d_ws, size_t ws_size,
                              hipStream_t stream) {
    const float* x     = (const float*)d_in[0];
    const float* w_src = (const float*)d_in[1];
    const float* b_src = (const float*)d_in[2];
    const float* w_dst = (const float*)d_in[3];
    const float* b_dst = (const float*)d_in[4];
    const float* attn  = (const float*)d_in[5];
    const int* src = (const int*)d_in[6];
    const int* dst = (const int*)d_in[7];

    char* ws = (char*)d_ws;
    // workspace layout (bytes):
    float* el    = (float*)(ws + 0);            // N*128 f32 = 51.2 MB
    float* er    = (float*)(ws + 51200000);     // 51.2 MB
    float* p_ex  = (float*)(ws + 102400000);    // E*4 f32  = 25.6 MB
    float* denom = (float*)(ws + 128000000);    // N*4 f32  = 1.6 MB
    float* acc   = (float*)(ws + 129600000);    // N*32 f32 = 12.8 MB
                                                // total 142.4 MB

    float* out0 = (float*)d_out;                // ft.mean: N*32 fp32
    float* out1 = out0 + N_NODES * DF;          // a.mean:  E fp32

    // zero denom + acc (contiguous 14.4 MB)
    (void)hipMemsetAsync(ws + 128000000, 0, 14400000, stream);

    k_gemm_valu<<<(N_NODES + 31) / 32, 256, 0, stream>>>(x, w_src, b_src, w_dst, b_dst, el, er);
    k_scores<<<E_EDGES / 8, 256, 0, stream>>>(src, dst, el, er, attn, p_ex, denom);
    k_aggregate<<<E_EDGES / 8, 256, 0, stream>>>(src, dst, el, p_ex, denom, acc, out1);
    k_finalize<<<(N_NODES * DF) / 256, 256, 0, stream>>>(acc, out0);
}

// Round 6
// 635.734 us; speedup vs baseline: 1.9561x; 1.9561x over previous
//
#include <hip/hip_runtime.h>
#include <hip/hip_bf16.h>

#define N_NODES 100000
#define E_EDGES 1600000
#define IN_F    256
#define HEADS   4
#define DF      32
#define HD      128           // HEADS*DF
#define NEG_SLOPE 0.2f

typedef __attribute__((ext_vector_type(8))) short  short8;   // 8 bf16 raw
typedef __attribute__((ext_vector_type(8))) unsigned short ushort8;
typedef __attribute__((ext_vector_type(4))) unsigned short ushort4v;
typedef __attribute__((ext_vector_type(4))) float  f32x4;

// rne fp32 -> bf16 split: v ~= hi + lo; returns (hi | lo<<16)
__device__ inline unsigned split_bf16(float v) {
    unsigned u  = __builtin_bit_cast(unsigned, v);
    unsigned hb = (u + 0x7FFFu + ((u >> 16) & 1u)) >> 16;
    float    hf = __builtin_bit_cast(float, hb << 16);
    float    l  = v - hf;
    unsigned ul = __builtin_bit_cast(unsigned, l);
    unsigned lb = (ul + 0x7FFFu + ((ul >> 16) & 1u)) >> 16;
    return (hb & 0xFFFFu) | (lb << 16);
}

// ------ 0. split+transpose weights ------
__global__ void k_prep_w(const float* __restrict__ wsrc,
                         const float* __restrict__ wdst,
                         unsigned short* __restrict__ wsT_hi,
                         unsigned short* __restrict__ wsT_lo,
                         unsigned short* __restrict__ wdT_hi,
                         unsigned short* __restrict__ wdT_lo) {
    int i = blockIdx.x * 256 + threadIdx.x;
    if (i >= IN_F * HD) return;
    int k = i >> 7, n = i & 127;
    unsigned p;
    p = split_bf16(wsrc[i]);
    wsT_hi[n * IN_F + k] = (unsigned short)(p & 0xFFFFu);
    wsT_lo[n * IN_F + k] = (unsigned short)(p >> 16);
    p = split_bf16(wdst[i]);
    wdT_hi[n * IN_F + k] = (unsigned short)(p & 0xFFFFu);
    wdT_lo[n * IN_F + k] = (unsigned short)(p >> 16);
}

// ------ 1. dual GEMM via hi/lo bf16 MFMA (validated R3: matches fp32 VALU) ------
#define BK  64
#define LDK (BK + 8)

__global__ void __launch_bounds__(256)
k_gemm(const float* __restrict__ x,
       const unsigned short* __restrict__ wsT_hi,
       const unsigned short* __restrict__ wsT_lo,
       const unsigned short* __restrict__ wdT_hi,
       const unsigned short* __restrict__ wdT_lo,
       const float* __restrict__ bsv,
       const float* __restrict__ bdv,
       float* __restrict__ el, float* __restrict__ er) {
    __shared__ unsigned short xs_hi[64][LDK];
    __shared__ unsigned short xs_lo[64][LDK];
    __shared__ unsigned short ws_hi[128][LDK];
    __shared__ unsigned short ws_lo[128][LDK];
    __shared__ unsigned short wd_hi[128][LDK];
    __shared__ unsigned short wd_lo[128][LDK];

    int tid  = threadIdx.x;
    int wave = tid >> 6, lane = tid & 63;
    int quad = lane >> 4, l16 = lane & 15;
    int rhalf = wave & 1, chalf = wave >> 1;
    int row0 = blockIdx.x * 64;

    f32x4 accS[2][4], accD[2][4];
    for (int a = 0; a < 2; ++a)
        for (int b = 0; b < 4; ++b) {
            accS[a][b] = (f32x4){0.f, 0.f, 0.f, 0.f};
            accD[a][b] = (f32x4){0.f, 0.f, 0.f, 0.f};
        }

    for (int kc = 0; kc < IN_F / BK; ++kc) {
        __syncthreads();
        for (int i = 0; i < 4; ++i) {
            int v = i * 256 + tid;
            int r = v >> 4, c = (v & 15) * 4;
            int gr = row0 + r;
            float4 val = make_float4(0.f, 0.f, 0.f, 0.f);
            if (gr < N_NODES)
                val = *(const float4*)(x + gr * IN_F + kc * BK + c);
            unsigned p0 = split_bf16(val.x);
            unsigned p1 = split_bf16(val.y);
            unsigned p2 = split_bf16(val.z);
            unsigned p3 = split_bf16(val.w);
            ushort4v h, l;
            h.x = (unsigned short)(p0 & 0xFFFFu); l.x = (unsigned short)(p0 >> 16);
            h.y = (unsigned short)(p1 & 0xFFFFu); l.y = (unsigned short)(p1 >> 16);
            h.z = (unsigned short)(p2 & 0xFFFFu); l.z = (unsigned short)(p2 >> 16);
            h.w = (unsigned short)(p3 & 0xFFFFu); l.w = (unsigned short)(p3 >> 16);
            *(ushort4v*)(&xs_hi[r][c]) = h;
            *(ushort4v*)(&xs_lo[r][c]) = l;
        }
        for (int i = 0; i < 4; ++i) {
            int v = i * 256 + tid;
            int n = v >> 3, c = (v & 7) * 8;
            int go = n * IN_F + kc * BK + c;
            *(ushort8*)(&ws_hi[n][c]) = *(const ushort8*)(wsT_hi + go);
            *(ushort8*)(&ws_lo[n][c]) = *(const ushort8*)(wsT_lo + go);
            *(ushort8*)(&wd_hi[n][c]) = *(const ushort8*)(wdT_hi + go);
            *(ushort8*)(&wd_lo[n][c]) = *(const ushort8*)(wdT_lo + go);
        }
        __syncthreads();

        for (int ks = 0; ks < 2; ++ks) {
            int kb = ks * 32 + quad * 8;
            int r0 = rhalf * 32 + l16, r1 = r0 + 16;
            short8 ah0 = *(const short8*)(&xs_hi[r0][kb]);
            short8 al0 = *(const short8*)(&xs_lo[r0][kb]);
            short8 ah1 = *(const short8*)(&xs_hi[r1][kb]);
            short8 al1 = *(const short8*)(&xs_lo[r1][kb]);
            for (int ct = 0; ct < 4; ++ct) {
                int n = chalf * 64 + ct * 16 + l16;
                short8 bsh = *(const short8*)(&ws_hi[n][kb]);
                short8 bsl = *(const short8*)(&ws_lo[n][kb]);
                short8 bdh = *(const short8*)(&wd_hi[n][kb]);
                short8 bdl = *(const short8*)(&wd_lo[n][kb]);
                accS[0][ct] = __builtin_amdgcn_mfma_f32_16x16x32_bf16(ah0, bsh, accS[0][ct], 0, 0, 0);
                accS[0][ct] = __builtin_amdgcn_mfma_f32_16x16x32_bf16(ah0, bsl, accS[0][ct], 0, 0, 0);
                accS[0][ct] = __builtin_amdgcn_mfma_f32_16x16x32_bf16(al0, bsh, accS[0][ct], 0, 0, 0);
                accS[1][ct] = __builtin_amdgcn_mfma_f32_16x16x32_bf16(ah1, bsh, accS[1][ct], 0, 0, 0);
                accS[1][ct] = __builtin_amdgcn_mfma_f32_16x16x32_bf16(ah1, bsl, accS[1][ct], 0, 0, 0);
                accS[1][ct] = __builtin_amdgcn_mfma_f32_16x16x32_bf16(al1, bsh, accS[1][ct], 0, 0, 0);
                accD[0][ct] = __builtin_amdgcn_mfma_f32_16x16x32_bf16(ah0, bdh, accD[0][ct], 0, 0, 0);
                accD[0][ct] = __builtin_amdgcn_mfma_f32_16x16x32_bf16(ah0, bdl, accD[0][ct], 0, 0, 0);
                accD[0][ct] = __builtin_amdgcn_mfma_f32_16x16x32_bf16(al0, bdh, accD[0][ct], 0, 0, 0);
                accD[1][ct] = __builtin_amdgcn_mfma_f32_16x16x32_bf16(ah1, bdh, accD[1][ct], 0, 0, 0);
                accD[1][ct] = __builtin_amdgcn_mfma_f32_16x16x32_bf16(ah1, bdl, accD[1][ct], 0, 0, 0);
                accD[1][ct] = __builtin_amdgcn_mfma_f32_16x16x32_bf16(al1, bdh, accD[1][ct], 0, 0, 0);
            }
        }
    }

    for (int ct = 0; ct < 4; ++ct) {
        int gc = chalf * 64 + ct * 16 + l16;
        float bsf = bsv[gc];
        float bdf = bdv[gc];
        for (int rt = 0; rt < 2; ++rt) {
            int gr0 = row0 + rhalf * 32 + rt * 16 + quad * 4;
            for (int r = 0; r < 4; ++r) {
                int gr = gr0 + r;
                if (gr < N_NODES) {
                    el[gr * HD + gc] = accS[rt][ct][r] + bsf;
                    er[gr * HD + gc] = accD[rt][ct][r] + bdf;
                }
            }
        }
    }
}

// ------ 2. CSR build ------
__global__ void __launch_bounds__(256)
k_hist(const int* __restrict__ dst, int* __restrict__ deg) {
    int e = blockIdx.x * 256 + threadIdx.x;
    if (e < E_EDGES) atomicAdd(&deg[dst[e]], 1);
}

// block-local inclusive scan: 256 thr x 4 items = 1024/block
__global__ void __launch_bounds__(256)
k_scan_a(const int* __restrict__ deg, int* __restrict__ tmp, int* __restrict__ bsum) {
    __shared__ int sc[256];
    int tid = threadIdx.x;
    int gi = blockIdx.x * 1024 + tid * 4;
    int d0 = (gi + 0 < N_NODES) ? deg[gi + 0] : 0;
    int d1 = (gi + 1 < N_NODES) ? deg[gi + 1] : 0;
    int d2 = (gi + 2 < N_NODES) ? deg[gi + 2] : 0;
    int d3 = (gi + 3 < N_NODES) ? deg[gi + 3] : 0;
    int s0 = d0, s1 = s0 + d1, s2 = s1 + d2, s3 = s2 + d3;
    sc[tid] = s3;
    __syncthreads();
    for (int off = 1; off < 256; off <<= 1) {
        int v = (tid >= off) ? sc[tid - off] : 0;
        __syncthreads();
        sc[tid] += v;
        __syncthreads();
    }
    int excl = sc[tid] - s3;
    if (gi + 0 < N_NODES) tmp[gi + 0] = excl + s0;
    if (gi + 1 < N_NODES) tmp[gi + 1] = excl + s1;
    if (gi + 2 < N_NODES) tmp[gi + 2] = excl + s2;
    if (gi + 3 < N_NODES) tmp[gi + 3] = excl + s3;
    if (tid == 255) bsum[blockIdx.x] = sc[255];
}

#define NBLK_SCAN ((N_NODES + 1023) / 1024)   // 98

__global__ void __launch_bounds__(256)
k_scan_b(int* __restrict__ bsum) {
    __shared__ int sc[256];
    int tid = threadIdx.x;
    int v = (tid < NBLK_SCAN) ? bsum[tid] : 0;
    sc[tid] = v;
    __syncthreads();
    for (int off = 1; off < 256; off <<= 1) {
        int u = (tid >= off) ? sc[tid - off] : 0;
        __syncthreads();
        sc[tid] += u;
        __syncthreads();
    }
    if (tid < NBLK_SCAN) bsum[tid] = sc[tid] - v;   // exclusive
}

// row_start[i] = exclusive scan; deg[i] overwritten as scatter cursor
__global__ void __launch_bounds__(256)
k_scan_c(const int* __restrict__ tmp, int* __restrict__ deg,
         const int* __restrict__ bsum, int* __restrict__ row_start) {
    int i = blockIdx.x * 256 + threadIdx.x;
    if (i >= N_NODES) return;
    int b = i >> 10;
    int incl = tmp[i] + bsum[b];
    int rs = incl - deg[i];
    row_start[i] = rs;
    deg[i] = rs;                       // cursor
    if (i == N_NODES - 1) row_start[N_NODES] = incl;
}

__global__ void __launch_bounds__(256)
k_scatter(const int* __restrict__ src, const int* __restrict__ dst,
          int* __restrict__ cursor, int* __restrict__ esrc, int* __restrict__ eord) {
    int e = blockIdx.x * 256 + threadIdx.x;
    if (e >= E_EDGES) return;
    int d = dst[e];
    int pos = atomicAdd(&cursor[d], 1);
    esrc[pos] = src[e];
    eord[pos] = e;
}

// ------ 3. fused per-node softmax + aggregate (no float atomics) ------
// 32 lanes per node, 8 nodes per 256-block; grid = N/8 = 12500 exact.
__global__ void __launch_bounds__(256)
k_node(const int* __restrict__ row_start,
       const int* __restrict__ esrc, const int* __restrict__ eord,
       const float* __restrict__ el, const float* __restrict__ er,
       const float* __restrict__ attn,
       float* __restrict__ p_ex,
       float* __restrict__ out0, float* __restrict__ out1) {
    int d = blockIdx.x * 8 + (threadIdx.x >> 5);
    int l = threadIdx.x & 31;
    int h = l >> 3;

    float4 rv = *(const float4*)(er + d * HD + l * 4);
    float4 av = *(const float4*)(attn + h * DF + (l & 7) * 4);

    int beg = row_start[d], end = row_start[d + 1];

    f32x4 acc = (f32x4){0.f, 0.f, 0.f, 0.f};
    float den = 0.f;

    for (int i = beg; i < end; ++i) {
        int s = esrc[i];
        float4 ev = *(const float4*)(el + s * HD + l * 4);
        float p = 0.f, tm;
        tm = ev.x + rv.x; tm = tm > 0.f ? tm : NEG_SLOPE * tm; p += av.x * tm;
        tm = ev.y + rv.y; tm = tm > 0.f ? tm : NEG_SLOPE * tm; p += av.y * tm;
        tm = ev.z + rv.z; tm = tm > 0.f ? tm : NEG_SLOPE * tm; p += av.z * tm;
        tm = ev.w + rv.w; tm = tm > 0.f ? tm : NEG_SLOPE * tm; p += av.w * tm;
        p += __shfl_xor(p, 1);
        p += __shfl_xor(p, 2);
        p += __shfl_xor(p, 4);
        float ex = expf(p);
        den += ex;
        acc.x += ex * ev.x; acc.y += ex * ev.y;
        acc.z += ex * ev.z; acc.w += ex * ev.w;
        if ((l & 7) == 0) p_ex[i * 4 + h] = ex;   // CSR-ordered
    }

    float rden = den > 0.f ? 1.0f / den : 0.f;
    f32x4 fa;
    fa.x = acc.x * rden * 0.25f; fa.y = acc.y * rden * 0.25f;
    fa.z = acc.z * rden * 0.25f; fa.w = acc.w * rden * 0.25f;
    fa.x += __shfl_xor(fa.x, 8); fa.x += __shfl_xor(fa.x, 16);
    fa.y += __shfl_xor(fa.y, 8); fa.y += __shfl_xor(fa.y, 16);
    fa.z += __shfl_xor(fa.z, 8); fa.z += __shfl_xor(fa.z, 16);
    fa.w += __shfl_xor(fa.w, 8); fa.w += __shfl_xor(fa.w, 16);
    if (l < 8) *(f32x4*)(out0 + d * DF + l * 4) = fa;

    // make p_ex stores visible within workgroup before pass 2
    __syncthreads();

    // broadcast per-head reciprocal denominators to all 32 lanes
    int base = threadIdx.x & 32;
    float r0 = __shfl(rden, base + 0);
    float r1 = __shfl(rden, base + 8);
    float r2 = __shfl(rden, base + 16);
    float r3 = __shfl(rden, base + 24);

    for (int i = beg + l; i < end; i += 32) {
        float4 exv = *(const float4*)(p_ex + i * 4);
        out1[eord[i]] = 0.25f * (exv.x * r0 + exv.y * r1 + exv.z * r2 + exv.w * r3);
    }
}

extern "C" void kernel_launch(void* const* d_in, const int* in_sizes, int n_in,
                              void* d_out, int out_size, void* d_ws, size_t ws_size,
                              hipStream_t stream) {
    const float* x     = (const float*)d_in[0];
    const float* w_src = (const float*)d_in[1];
    const float* b_src = (const float*)d_in[2];
    const float* w_dst = (const float*)d_in[3];
    const float* b_dst = (const float*)d_in[4];
    const float* attn  = (const float*)d_in[5];
    const int* src = (const int*)d_in[6];
    const int* dst = (const int*)d_in[7];

    char* ws = (char*)d_ws;
    float* el        = (float*)(ws + 0);             // 51.2 MB
    float* er        = (float*)(ws + 51200000);      // 51.2 MB
    float* p_ex      = (float*)(ws + 102400000);     // 25.6 MB (CSR order)
    int*   deg       = (int*)(ws + 128000000);       // 400 KB (later: cursor)
    int*   tmp       = (int*)(ws + 128400000);       // 400 KB
    int*   bsum      = (int*)(ws + 128800000);       // 4 KB
    int*   row_start = (int*)(ws + 128804096);       // 400 KB
    int*   esrc      = (int*)(ws + 129204224);       // 6.4 MB
    int*   eord      = (int*)(ws + 135604224);       // 6.4 MB
    unsigned short* wsT_hi = (unsigned short*)(ws + 142004224);  // 64 KB each
    unsigned short* wsT_lo = (unsigned short*)(ws + 142069760);
    unsigned short* wdT_hi = (unsigned short*)(ws + 142135296);
    unsigned short* wdT_lo = (unsigned short*)(ws + 142200832);

    float* out0 = (float*)d_out;                // ft.mean: N*32 fp32
    float* out1 = out0 + N_NODES * DF;          // a.mean:  E fp32

    (void)hipMemsetAsync(deg, 0, N_NODES * sizeof(int), stream);

    k_prep_w<<<128, 256, 0, stream>>>(w_src, w_dst, wsT_hi, wsT_lo, wdT_hi, wdT_lo);
    k_gemm<<<(N_NODES + 63) / 64, 256, 0, stream>>>(x, wsT_hi, wsT_lo, wdT_hi, wdT_lo,
                                                    b_src, b_dst, el, er);
    k_hist<<<(E_EDGES + 255) / 256, 256, 0, stream>>>(dst, deg);
    k_scan_a<<<NBLK_SCAN, 256, 0, stream>>>(deg, tmp, bsum);
    k_scan_b<<<1, 256, 0, stream>>>(bsum);
    k_scan_c<<<(N_NODES + 255) / 256, 256, 0, stream>>>(tmp, deg, bsum, row_start);
    k_scatter<<<(E_EDGES + 255) / 256, 256, 0, stream>>>(src, dst, deg, esrc, eord);
    k_node<<<N_NODES / 8, 256, 0, stream>>>(row_start, esrc, eord, el, er, attn,
                                            p_ex, out0, out1);
}